// Round 5
// baseline (35.848 us; speedup 1.0000x reference)
//
#include <hip/hip_runtime.h>
#include <math.h>

#define EPS 1e-6f
#define LOG2E 1.4426950408889634f

constexpr int TB  = 256;   // threads/block (4 waves)
constexpr int TD  = 256;   // dense tile dim (1 i-row/thread, TD j's in LDS)
constexpr int EPT = 8;     // edges per thread

// Single fused kernel. Blocks [0, nd): dense triangular tile-pairs (longest,
// dispatched first). Blocks [nd, nd+ne): edge chunks. Each block writes a
// pre-weighted partial (dense: x-0.5 diag / x-1.0 off-diag; edge: +1), then
// signals a device-scope done-counter. The last block to signal performs the
// final fp64 reduction over part[] in FIXED index order (deterministic no
// matter which block runs it) and writes out[0].
//
// Inner loop: DIFFERENCE form (d2 >= 0 structurally — the dot-product
// expansion NaN'd in R3). Coordinates pre-scaled by log2(e): exp(-r) is one
// v_exp_f32 with free VOP3 negate. Per 64 pairs: 2 trans + 5 VALU + 1
// broadcast ds_read_b128 -> trans-pipe bound (~16 cyc / 64 pairs).
__global__ void __launch_bounds__(TB) k_fused(
    const float2* __restrict__ Z, const float* __restrict__ gamma,
    const int* __restrict__ ei, const int* __restrict__ ej,
    float* __restrict__ part, unsigned* __restrict__ cnt,
    float* __restrict__ out, int n, int nb, int nd, int e, int np)
{
    __shared__ float4 sj[TD];
    __shared__ float wsum[TB / 64];
    __shared__ unsigned s_old;
    const int bx = blockIdx.x;
    float acc = 0.f;
    float blockw = 1.f;

    if (bx < nd) {
        // ---- dense role: decode triangular index -> (a,b), b >= a ----
        auto before = [nb](int x) { return x * nb - (x * (x - 1)) / 2; };
        int a = (int)(((2 * nb + 1) -
                       sqrtf((float)((2 * nb + 1) * (2 * nb + 1) - 8 * bx))) * 0.5f);
        if (a < 0) a = 0;
        if (a > nb - 1) a = nb - 1;
        while (before(a + 1) <= bx) ++a;
        while (before(a) > bx) --a;
        const int b = a + (bx - before(a));

        const int j0 = b * TD;
        const int jn = min(TD, n - j0);

        if (threadIdx.x < jn) {
            const int j = j0 + threadIdx.x;
            float2 z = Z[j];
            sj[threadIdx.x] = make_float4(z.x * LOG2E, z.y * LOG2E,
                                          __expf(gamma[j]), 0.f);
        }
        __syncthreads();

        const int i = a * TD + threadIdx.x;
        if (i < n) {
            float2 zi = Z[i];
            const float ax = (zi.x + EPS) * LOG2E;
            const float ay = (zi.y + EPS) * LOG2E;
            #pragma unroll 8
            for (int k = 0; k < jn; ++k) {
                float4 s = sj[k];
                float dx = ax - s.x;
                float dy = ay - s.y;
                float r = __builtin_amdgcn_sqrtf(fmaf(dx, dx, dy * dy));
                acc = fmaf(s.z, __builtin_amdgcn_exp2f(-r), acc);
            }
            float egi = __expf(gamma[i]);
            if (a == b) acc -= egi * 0.9999985858f;  // exp(-sqrt(2)*EPS)
            acc *= egi;
        }
        blockw = (a == b) ? -0.5f : -1.0f;
    } else {
        // ---- edge role ----
        const int c = bx - nd;
        const long base = ((long)c * TB + threadIdx.x) * EPT;
        if (base + EPT <= e) {
            int4 ia0 = *(const int4*)(ei + base);
            int4 ia1 = *(const int4*)(ei + base + 4);
            int4 ja0 = *(const int4*)(ej + base);
            int4 ja1 = *(const int4*)(ej + base + 4);
            const int as[EPT] = {ia0.x, ia0.y, ia0.z, ia0.w,
                                 ia1.x, ia1.y, ia1.z, ia1.w};
            const int bs[EPT] = {ja0.x, ja0.y, ja0.z, ja0.w,
                                 ja1.x, ja1.y, ja1.z, ja1.w};
            #pragma unroll
            for (int k = 0; k < EPT; ++k) {
                float2 za = Z[as[k]], zb = Z[bs[k]];
                float dx = za.x - zb.x + EPS;
                float dy = za.y - zb.y + EPS;
                float r = __builtin_amdgcn_sqrtf(fmaf(dx, dx, dy * dy));
                acc += gamma[as[k]] + gamma[bs[k]] - r;
            }
        } else {
            for (int k = 0; k < EPT; ++k) {
                long idx = base + k;
                if (idx < e) {
                    int ai = ei[idx], bi = ej[idx];
                    float2 za = Z[ai], zb = Z[bi];
                    float dx = za.x - zb.x + EPS;
                    float dy = za.y - zb.y + EPS;
                    float r = __builtin_amdgcn_sqrtf(fmaf(dx, dx, dy * dy));
                    acc += gamma[ai] + gamma[bi] - r;
                }
            }
        }
        blockw = 1.f;
    }

    // fixed-order deterministic block reduction
    for (int off = 32; off > 0; off >>= 1) acc += __shfl_down(acc, off, 64);
    const int lane = threadIdx.x & 63, w = threadIdx.x >> 6;
    if (lane == 0) wsum[w] = acc;
    __syncthreads();
    if (threadIdx.x == 0) {
        float s = 0.f;
        #pragma unroll
        for (int k = 0; k < TB / 64; ++k) s += wsum[k];
        part[bx] = blockw * s;
        __threadfence();                         // release: flush part[bx] device-wide
        s_old = atomicAdd(cnt, 1u);              // device-scope signal
    }
    __syncthreads();

    if (s_old == (unsigned)(np - 1)) {
        // ---- last block: final fp64 reduction, fixed index order ----
        __threadfence();                         // acquire: see all part[] stores
        double sd = 0.0;
        for (int t = threadIdx.x; t < np; t += TB) sd += (double)part[t];
        __shared__ double sh[TB];
        sh[threadIdx.x] = sd;
        __syncthreads();
        for (int s = TB / 2; s > 0; s >>= 1) {
            if (threadIdx.x < s) sh[threadIdx.x] += sh[threadIdx.x + s];
            __syncthreads();
        }
        if (threadIdx.x == 0) out[0] = (float)sh[0];
    }
}

extern "C" void kernel_launch(void* const* d_in, const int* in_sizes, int n_in,
                              void* d_out, int out_size, void* d_ws, size_t ws_size,
                              hipStream_t stream)
{
    const float2* Z     = (const float2*)d_in[0];
    const float*  gamma = (const float*)d_in[1];
    const int*    ei    = (const int*)d_in[2];
    const int*    ej    = (const int*)d_in[3];
    const int n = in_sizes[1];
    const int e = in_sizes[2];
    float* out = (float*)d_out;

    const int nb = (n + TD - 1) / TD;
    const int nd = nb * (nb + 1) / 2;
    const int ne = (e + TB * EPT - 1) / (TB * EPT);
    const int np = nd + ne;

    float*    part = (float*)d_ws;
    unsigned* cnt  = (unsigned*)(part + np);

    // counter must be 0 at the start of every call (ws is poisoned once and
    // never re-poisoned between replays) — 4-byte memset node, capture-safe.
    hipMemsetAsync(cnt, 0, sizeof(unsigned), stream);

    hipLaunchKernelGGL(k_fused, dim3(np), dim3(TB), 0, stream,
                       Z, gamma, ei, ej, part, cnt, out, n, nb, nd, e, np);
}